// Round 20
// baseline (130.680 us; speedup 1.0000x reference)
//
#include <hip/hip_runtime.h>
#include <math.h>

#define BB  8
#define HH  512
#define WW  512
#define HW  (HH*WW)

#define NT  512          // threads per block (8 waves)
#define TSX 32           // tile width
#define TSY 32           // tile height
#define GR  34           // guidance tile (halo 1)
#define GS2 36           // packed guidance row stride (u32 words)
#define FBWORDS (GR*GS2) // fb-plane words (w-plane follows)
#define FR  36           // flow tile (halo 2)
#define FPS2 37          // flow row stride (float2 units)

typedef __attribute__((ext_vector_type(8))) short  short8;
typedef __attribute__((ext_vector_type(4))) float  float4v;
typedef __attribute__((ext_vector_type(2))) float  float2v;
typedef __attribute__((ext_vector_type(2), aligned(4))) float float2u; // 4B-aligned pair
typedef __attribute__((ext_vector_type(4))) int    int4v;
typedef __attribute__((ext_vector_type(4))) uint   uint4v;

#define MFMA16x32(a,b,c) __builtin_amdgcn_mfma_f32_16x16x32_bf16((a),(b),(c),0,0,0)

// launder: force materialization (anti-remat)
template <typename T>
static __device__ __forceinline__ void keep(T& x) { asm volatile("" : "+v"(x)); }

static __device__ __forceinline__ uint  fu(float f) { return __float_as_uint(f); }
static __device__ __forceinline__ float uf(uint u)  { return __uint_as_float(u); }

static __device__ __forceinline__ ushort f2bf_rne(float f) {
    uint u = fu(f);
    u += 0x7fffu + ((u >> 16) & 1u);
    return (ushort)(u >> 16);
}
static __device__ __forceinline__ void split_rne(float f, ushort& hi, ushort& lo) {
    hi = f2bf_rne(f);
    float r = f - uf((uint)hi << 16);
    lo = f2bf_rne(r);
}

// conv2 row-permutation tap (verified r7-r19)
static __device__ __forceinline__ int tap_kk(int mtodd, int qr, int rr) {
    if (!mtodd) return 5 * qr + rr;
    if (rr == 0) return 5 * qr + 4;
    if (rr == 1) return 20 + qr;
    if (rr == 2 && qr == 3) return 24;
    return -1;
}

// conv1 K-slot -> original k (pair-packed scheme, verified r10-r19)
static __device__ __forceinline__ int slot_k(int q, int i) {
    const int p = 4 * q + (i >> 1), e = i & 1;
    if (p <= 8)  return e ? 9 + p : p;
    if (p <= 11) return 18 + 3 * (p - 9) + e;
    if (p <= 14) return e ? -1 : 18 + 3 * (p - 12) + 2;
    return -1;
}

// ===================== setup: per-lane MFMA params -> ws =====================
__global__ __launch_bounds__(64)
void setup_params(const float* __restrict__ w1, const float* __restrict__ b1,
                  const float* __restrict__ w2, const float* __restrict__ b2,
                  uint4v* __restrict__ ws)
{
    const int L = threadIdx.x;
    const int c = L & 15, q = L >> 4;

    #pragma unroll
    for (int t = 0; t < 2; ++t) {
        short8 hi8, lo8;
        #pragma unroll
        for (int i = 0; i < 8; ++i) {
            const int k = slot_k(q, i);
            const float f = (k >= 0) ? w1[(16 * t + c) * 27 + k] : 0.f;
            ushort h_, l_; split_rne(f, h_, l_);
            hi8[i] = (short)h_; lo8[i] = (short)l_;
        }
        *reinterpret_cast<short8*>(&ws[(0 + t) * 64 + L]) = hi8;
        *reinterpret_cast<short8*>(&ws[(2 + t) * 64 + L]) = lo8;
    }
    #pragma unroll
    for (int mt = 0; mt < 4; ++mt) {
        const int ch = mt >> 1;
        const int kk = tap_kk(mt & 1, c >> 2, c & 3);
        short8 a8;
        #pragma unroll
        for (int i = 0; i < 8; ++i) {
            const int oc = (i < 4) ? (4 * q + i) : (16 + 4 * q + (i - 4));
            const float f = (kk >= 0) ? w2[(25 * ch + kk) * 32 + oc] : 0.f;
            a8[i] = (short)f2bf_rne(f);
        }
        *reinterpret_cast<short8*>(&ws[(4 + mt) * 64 + L]) = a8;
    }
    #pragma unroll
    for (int t = 0; t < 2; ++t) {
        float4v v;
        #pragma unroll
        for (int r = 0; r < 4; ++r) v[r] = b1[16 * t + 4 * q + r];
        *reinterpret_cast<float4v*>(&ws[(12 + t) * 64 + L]) = v;
    }
    #pragma unroll
    for (int mt = 0; mt < 4; ++mt) {
        const int ch = mt >> 1;
        float4v v;
        #pragma unroll
        for (int r = 0; r < 4; ++r) {
            const int kk = tap_kk(mt & 1, q, r);
            v[r] = (kk >= 0) ? b2[25 * ch + kk] : 0.f;
        }
        *reinterpret_cast<float4v*>(&ws[(14 + mt) * 64 + L]) = v;
    }
    {
        int4v o;
        #pragma unroll
        for (int pl = 0; pl < 4; ++pl) {
            const int p = 4 * q + pl;
            int off;
            if (p <= 8)       off = (p / 3) * GS2 + (p % 3);        // FB word
            else if (p <= 11) off = FBWORDS + (p - 9) * GS2;        // W (ky,0)
            else if (p <= 14) off = FBWORDS + (p - 12) * GS2 + 2;   // W (ky,2)
            else              off = FBWORDS;                        // pad (dead)
            o[pl] = off;
        }
        *reinterpret_cast<int4v*>(&ws[18 * 64 + L]) = o;
    }
}

// ====== fused: 512-thread block, 8 waves on one 32x32 tile ======
__global__ __launch_bounds__(NT, 8)
void fused_kernel(const float* __restrict__ v0,
                  const float* __restrict__ v2,
                  const uint4v* __restrict__ P,
                  float* __restrict__ out)
{
    __shared__ uint    g32[2 * FBWORDS];          // fb-pair plane | w-pair plane
    __shared__ float2v f2[FR * FPS2];             // flow tile, channels interleaved

    const int bx0 = blockIdx.x * TSX;
    const int by0 = blockIdx.y * TSY;
    const int b   = blockIdx.z;
    const int tid = threadIdx.x;
    const int w   = tid >> 6;                     // wave 0..7
    const int L   = tid & 63;
    const int c   = L & 15;
    const int q   = L >> 4;

    const float* v0b = v0 + (size_t)b * 2 * HW;
    const float* v2b = v2 + (size_t)b * 2 * HW;

    // ---- per-lane params (loaded once) ----
    short8 a1h[2], a1l[2], a2[4];
    #pragma unroll
    for (int t = 0; t < 2; ++t) {
        a1h[t] = *reinterpret_cast<const short8*>(&P[(0 + t) * 64 + L]); keep(a1h[t]);
        a1l[t] = *reinterpret_cast<const short8*>(&P[(2 + t) * 64 + L]); keep(a1l[t]);
    }
    #pragma unroll
    for (int mt = 0; mt < 4; ++mt) {
        a2[mt] = *reinterpret_cast<const short8*>(&P[(4 + mt) * 64 + L]); keep(a2[mt]);
    }
    float4v bi1[2], bi2[4];
    #pragma unroll
    for (int t = 0; t < 2; ++t) {
        bi1[t] = *reinterpret_cast<const float4v*>(&P[(12 + t) * 64 + L]); keep(bi1[t]);
    }
    #pragma unroll
    for (int mt = 0; mt < 4; ++mt) {
        bi2[mt] = *reinterpret_cast<const float4v*>(&P[(14 + mt) * 64 + L]); keep(bi2[mt]);
    }
    int off1[4];
    {
        int4v o = *reinterpret_cast<const int4v*>(&P[18 * 64 + L]); keep(o);
        #pragma unroll
        for (int pl = 0; pl < 4; ++pl) off1[pl] = o[pl];
    }

    // ---- single staging loop over flow tile (36x36=1296, 3 predicated trips).
    // Flow write always; guidance for interior 34x34 reuses in-register v0.
    ushort* w16 = reinterpret_cast<ushort*>(g32 + FBWORDS);
    #pragma unroll
    for (int k = 0; k < 3; ++k) {
        const int i = tid + k * NT;
        if (i < FR * FR) {
            const int ly = i / FR, lx = i - (i / FR) * FR;
            const int y = by0 - 2 + ly, x = bx0 - 2 + lx;
            const bool inimg = (unsigned)y < HH && (unsigned)x < WW;
            float f0 = 0.f, f1 = 0.f;
            if (inimg) {
                f0 = v0b[y * WW + x];
                f1 = v0b[HW + y * WW + x];
            }
            float2v p; p[0] = f0; p[1] = f1;
            f2[ly * FPS2 + lx] = p;

            // guidance for interior items (r = ly-1, cc = lx-1)
            if (ly >= 1 && ly <= GR && lx >= 1 && lx <= GR) {
                const int r = ly - 1, cc = lx - 1;
                uint fbw = 0u;
                ushort wv16 = 0;
                if (inimg) {
                    const float sgx = (-1.0f + x * (2.0f / (WW - 1))) + f0 * (2.0f / WW);
                    const float sgy = (-1.0f + y * (2.0f / (HH - 1))) + f1 * (2.0f / HH);
                    const float ixf = (sgx + 1.0f) * (0.5f * (WW - 1));
                    const float iyf = (sgy + 1.0f) * (0.5f * (HH - 1));
                    const float x0f = floorf(ixf), y0f = floorf(iyf);
                    const int   x0  = (int)x0f,   y0i = (int)y0f;
                    const float wx1 = ixf - x0f, wx0 = 1.0f - wx1;
                    const float wy1 = iyf - y0f, wy0 = 1.0f - wy1;
                    float s0 = 0.f, s1 = 0.f;
                    if (x0 >= 0 && x0 + 1 < WW && y0i >= 0 && y0i + 1 < HH) {
                        const int i00 = y0i * WW + x0;
                        const float2u c0a = *reinterpret_cast<const float2u*>(v2b + i00);
                        const float2u c0b = *reinterpret_cast<const float2u*>(v2b + i00 + WW);
                        const float2u c1a = *reinterpret_cast<const float2u*>(v2b + HW + i00);
                        const float2u c1b = *reinterpret_cast<const float2u*>(v2b + HW + i00 + WW);
                        const float w00 = wy0 * wx0, w01 = wy0 * wx1;
                        const float w10 = wy1 * wx0, w11 = wy1 * wx1;
                        s0 = fmaf(w00, c0a[0], s0);  s1 = fmaf(w00, c1a[0], s1);
                        s0 = fmaf(w01, c0a[1], s0);  s1 = fmaf(w01, c1a[1], s1);
                        s0 = fmaf(w10, c0b[0], s0);  s1 = fmaf(w10, c1b[0], s1);
                        s0 = fmaf(w11, c0b[1], s0);  s1 = fmaf(w11, c1b[1], s1);
                    } else {
                        #pragma unroll
                        for (int cy = 0; cy < 2; ++cy) {
                            const int yc = y0i + cy;
                            const float wy = cy ? wy1 : wy0;
                            if (yc >= 0 && yc < HH) {
                                #pragma unroll
                                for (int cx = 0; cx < 2; ++cx) {
                                    const int xc = x0 + cx;
                                    if (xc >= 0 && xc < WW) {
                                        const float wgt = wy * (cx ? wx1 : wx0);
                                        const int i2 = yc * WW + xc;
                                        s0 = fmaf(wgt, v2b[i2], s0);
                                        s1 = fmaf(wgt, v2b[HW + i2], s1);
                                    }
                                }
                            }
                        }
                    }
                    const float fb0 = f0 + s0;
                    const float fb1 = f1 + s1;
                    const float wv  = __expf(-sqrtf(fmaf(fb0, fb0, fb1 * fb1)));
                    fbw  = (uint)f2bf_rne(fb0) | ((uint)f2bf_rne(fb1) << 16);
                    wv16 = f2bf_rne(wv);
                }
                g32[r * GS2 + cc] = fbw;
                const int rowb = r * (2 * GS2);
                w16[rowb + 2 * cc] = wv16;
                if (cc > 0)   w16[rowb + 2 * cc - 1] = wv16; // high half of word cc-1
                if (cc == 33) w16[rowb + 67] = 0;            // dead element: keep finite
            }
        }
    }
    __syncthreads();

    // ---- 8 groups of 16 px per wave (wave w owns rows 4w..4w+3) ----
    #pragma unroll 2
    for (int g = 0; g < 8; ++g) {
        const int py = 4 * w + (g >> 1);
        const int px = 16 * (g & 1) + c;
        const int gb = py * GS2 + px;

        // B1 frag: 4 u32 word gathers -> short8
        uint4v uw;
        #pragma unroll
        for (int pl = 0; pl < 4; ++pl) uw[pl] = g32[off1[pl] + gb];
        const short8 b1 = *reinterpret_cast<const short8*>(&uw);

        // conv3x3 GEMM (bf16 B, split A), bias in C
        float4v acc1_0 = bi1[0], acc1_1 = bi1[1];
        acc1_0 = MFMA16x32(a1l[0], b1, acc1_0);
        acc1_0 = MFMA16x32(a1h[0], b1, acc1_0);
        acc1_1 = MFMA16x32(a1l[1], b1, acc1_1);
        acc1_1 = MFMA16x32(a1h[1], b1, acc1_1);

        // ReLU + truncation bf16 (hi only; headroom verified) -> conv2 B frag
        short8 b2h;
        #pragma unroll
        for (int r = 0; r < 4; ++r) {
            const float h0 = fmaxf(acc1_0[r], 0.f);
            const float h1 = fmaxf(acc1_1[r], 0.f);
            b2h[r]     = (short)(fu(h0) >> 16);
            b2h[4 + r] = (short)(fu(h1) >> 16);
        }

        // conv1x1 GEMM via K-permuted 16x16x32, hi term only (4 MFMA)
        float4v acc2[4] = {bi2[0], bi2[1], bi2[2], bi2[3]};
        #pragma unroll
        for (int mt = 0; mt < 4; ++mt)
            acc2[mt] = MFMA16x32(a2[mt], b2h, acc2[mt]);

        // combine: 7 x ds_read_b64 (both channels per read), compile-time offsets
        const int pyb   = py * FPS2 + px;
        const int base0 = pyb + q * FPS2;         // taps (q, 0..4)
        const int b4    = pyb + 4 * FPS2 + q;     // tap  (4, q)

        const float2v p0 = f2[base0];
        const float2v p1 = f2[base0 + 1];
        const float2v p2 = f2[base0 + 2];
        const float2v p3 = f2[base0 + 3];
        const float2v p4 = f2[base0 + 4];
        const float2v pb = f2[b4];
        const float2v pc = f2[base0 + 41];        // (4,4): kern==0 unless q==3

        float s0 = 0.f, s1 = 0.f;
        s0 = fmaf(acc2[0][0], p0[0], s0);  s1 = fmaf(acc2[2][0], p0[1], s1);
        s0 = fmaf(acc2[0][1], p1[0], s0);  s1 = fmaf(acc2[2][1], p1[1], s1);
        s0 = fmaf(acc2[0][2], p2[0], s0);  s1 = fmaf(acc2[2][2], p2[1], s1);
        s0 = fmaf(acc2[0][3], p3[0], s0);  s1 = fmaf(acc2[2][3], p3[1], s1);
        s0 = fmaf(acc2[1][0], p4[0], s0);  s1 = fmaf(acc2[3][0], p4[1], s1);
        s0 = fmaf(acc2[1][1], pb[0], s0);  s1 = fmaf(acc2[3][1], pb[1], s1);
        s0 = fmaf(acc2[1][2], pc[0], s0);  s1 = fmaf(acc2[3][2], pc[1], s1);

        s0 += __shfl_xor(s0, 16);
        s0 += __shfl_xor(s0, 32);
        s1 += __shfl_xor(s1, 16);
        s1 += __shfl_xor(s1, 32);

        if (q == 0) {
            const int y = by0 + py, x = bx0 + px;
            out[((size_t)b * 2 + 0) * HW + y * WW + x] = s0;
            out[((size_t)b * 2 + 1) * HW + y * WW + x] = s1;
        }
    }
}

extern "C" void kernel_launch(void* const* d_in, const int* in_sizes, int n_in,
                              void* d_out, int out_size, void* d_ws, size_t ws_size,
                              hipStream_t stream) {
    const float* v0 = (const float*)d_in[0];
    const float* v2 = (const float*)d_in[1];
    const float* w1 = (const float*)d_in[2];
    const float* b1 = (const float*)d_in[3];
    const float* w2 = (const float*)d_in[4];
    const float* b2 = (const float*)d_in[5];
    uint4v* ws = (uint4v*)d_ws;

    setup_params<<<1, 64, 0, stream>>>(w1, b1, w2, b2, ws);

    dim3 grid(WW / TSX, HH / TSY, BB);
    fused_kernel<<<grid, dim3(NT, 1, 1), 0, stream>>>(v0, v2, ws, (float*)d_out);
}

// Round 21
// 57.467 us; speedup vs baseline: 2.2740x; 2.2740x over previous
//
#include <hip/hip_runtime.h>
#include <math.h>

#define BB  8
#define HH  512
#define WW  512
#define HW  (HH*WW)

#define NT  512          // threads per block (8 waves)
#define TSX 32           // tile width
#define TSY 32           // tile height
#define GR  34           // guidance tile (halo 1)
#define GS2 36           // packed guidance row stride (u32 words)
#define FBWORDS (GR*GS2) // fb-plane words (w-plane follows)
#define FR  36           // flow tile (halo 2)
#define FPS2 37          // flow row stride (float2 units)

typedef __attribute__((ext_vector_type(8))) short  short8;
typedef __attribute__((ext_vector_type(4))) float  float4v;
typedef __attribute__((ext_vector_type(2))) float  float2v;
typedef __attribute__((ext_vector_type(2), aligned(4))) float float2u; // 4B-aligned pair
typedef __attribute__((ext_vector_type(4))) int    int4v;
typedef __attribute__((ext_vector_type(4))) uint   uint4v;

#define MFMA16x32(a,b,c) __builtin_amdgcn_mfma_f32_16x16x32_bf16((a),(b),(c),0,0,0)

// launder: force materialization (anti-remat)
template <typename T>
static __device__ __forceinline__ void keep(T& x) { asm volatile("" : "+v"(x)); }

static __device__ __forceinline__ uint  fu(float f) { return __float_as_uint(f); }
static __device__ __forceinline__ float uf(uint u)  { return __uint_as_float(u); }

static __device__ __forceinline__ ushort f2bf_rne(float f) {
    uint u = fu(f);
    u += 0x7fffu + ((u >> 16) & 1u);
    return (ushort)(u >> 16);
}
static __device__ __forceinline__ void split_rne(float f, ushort& hi, ushort& lo) {
    hi = f2bf_rne(f);
    float r = f - uf((uint)hi << 16);
    lo = f2bf_rne(r);
}

// conv2 row-permutation tap (verified r7-r19)
static __device__ __forceinline__ int tap_kk(int mtodd, int qr, int rr) {
    if (!mtodd) return 5 * qr + rr;
    if (rr == 0) return 5 * qr + 4;
    if (rr == 1) return 20 + qr;
    if (rr == 2 && qr == 3) return 24;
    return -1;
}

// conv1 K-slot -> original k (pair-packed scheme, verified r10-r19)
static __device__ __forceinline__ int slot_k(int q, int i) {
    const int p = 4 * q + (i >> 1), e = i & 1;
    if (p <= 8)  return e ? 9 + p : p;
    if (p <= 11) return 18 + 3 * (p - 9) + e;
    if (p <= 14) return e ? -1 : 18 + 3 * (p - 12) + 2;
    return -1;
}

// ===================== setup: per-lane MFMA params -> ws =====================
__global__ __launch_bounds__(64)
void setup_params(const float* __restrict__ w1, const float* __restrict__ b1,
                  const float* __restrict__ w2, const float* __restrict__ b2,
                  uint4v* __restrict__ ws)
{
    const int L = threadIdx.x;
    const int c = L & 15, q = L >> 4;

    #pragma unroll
    for (int t = 0; t < 2; ++t) {
        short8 hi8, lo8;
        #pragma unroll
        for (int i = 0; i < 8; ++i) {
            const int k = slot_k(q, i);
            const float f = (k >= 0) ? w1[(16 * t + c) * 27 + k] : 0.f;
            ushort h_, l_; split_rne(f, h_, l_);
            hi8[i] = (short)h_; lo8[i] = (short)l_;
        }
        *reinterpret_cast<short8*>(&ws[(0 + t) * 64 + L]) = hi8;
        *reinterpret_cast<short8*>(&ws[(2 + t) * 64 + L]) = lo8;
    }
    #pragma unroll
    for (int mt = 0; mt < 4; ++mt) {
        const int ch = mt >> 1;
        const int kk = tap_kk(mt & 1, c >> 2, c & 3);
        short8 a8;
        #pragma unroll
        for (int i = 0; i < 8; ++i) {
            const int oc = (i < 4) ? (4 * q + i) : (16 + 4 * q + (i - 4));
            const float f = (kk >= 0) ? w2[(25 * ch + kk) * 32 + oc] : 0.f;
            a8[i] = (short)f2bf_rne(f);
        }
        *reinterpret_cast<short8*>(&ws[(4 + mt) * 64 + L]) = a8;
    }
    #pragma unroll
    for (int t = 0; t < 2; ++t) {
        float4v v;
        #pragma unroll
        for (int r = 0; r < 4; ++r) v[r] = b1[16 * t + 4 * q + r];
        *reinterpret_cast<float4v*>(&ws[(12 + t) * 64 + L]) = v;
    }
    #pragma unroll
    for (int mt = 0; mt < 4; ++mt) {
        const int ch = mt >> 1;
        float4v v;
        #pragma unroll
        for (int r = 0; r < 4; ++r) {
            const int kk = tap_kk(mt & 1, q, r);
            v[r] = (kk >= 0) ? b2[25 * ch + kk] : 0.f;
        }
        *reinterpret_cast<float4v*>(&ws[(14 + mt) * 64 + L]) = v;
    }
    {
        int4v o;
        #pragma unroll
        for (int pl = 0; pl < 4; ++pl) {
            const int p = 4 * q + pl;
            int off;
            if (p <= 8)       off = (p / 3) * GS2 + (p % 3);        // FB word
            else if (p <= 11) off = FBWORDS + (p - 9) * GS2;        // W (ky,0)
            else if (p <= 14) off = FBWORDS + (p - 12) * GS2 + 2;   // W (ky,2)
            else              off = FBWORDS;                        // pad (dead)
            o[pl] = off;
        }
        *reinterpret_cast<int4v*>(&ws[18 * 64 + L]) = o;
    }
}

// ====== fused: 512-thread block, 8 waves on one 32x32 tile (VGPR cap 128) ======
__global__ __launch_bounds__(NT, 4)
void fused_kernel(const float* __restrict__ v0,
                  const float* __restrict__ v2,
                  const uint4v* __restrict__ P,
                  float* __restrict__ out)
{
    __shared__ uint    g32[2 * FBWORDS];          // fb-pair plane | w-pair plane
    __shared__ float2v f2[FR * FPS2];             // flow tile, channels interleaved

    const int bx0 = blockIdx.x * TSX;
    const int by0 = blockIdx.y * TSY;
    const int b   = blockIdx.z;
    const int tid = threadIdx.x;
    const int w   = tid >> 6;                     // wave 0..7
    const int L   = tid & 63;
    const int c   = L & 15;
    const int q   = L >> 4;

    const float* v0b = v0 + (size_t)b * 2 * HW;
    const float* v2b = v2 + (size_t)b * 2 * HW;

    // ---- per-lane params (loaded once) ----
    short8 a1h[2], a1l[2], a2[4];
    #pragma unroll
    for (int t = 0; t < 2; ++t) {
        a1h[t] = *reinterpret_cast<const short8*>(&P[(0 + t) * 64 + L]); keep(a1h[t]);
        a1l[t] = *reinterpret_cast<const short8*>(&P[(2 + t) * 64 + L]); keep(a1l[t]);
    }
    #pragma unroll
    for (int mt = 0; mt < 4; ++mt) {
        a2[mt] = *reinterpret_cast<const short8*>(&P[(4 + mt) * 64 + L]); keep(a2[mt]);
    }
    float4v bi1[2], bi2[4];
    #pragma unroll
    for (int t = 0; t < 2; ++t) {
        bi1[t] = *reinterpret_cast<const float4v*>(&P[(12 + t) * 64 + L]); keep(bi1[t]);
    }
    #pragma unroll
    for (int mt = 0; mt < 4; ++mt) {
        bi2[mt] = *reinterpret_cast<const float4v*>(&P[(14 + mt) * 64 + L]); keep(bi2[mt]);
    }
    int off1[4];
    {
        int4v o = *reinterpret_cast<const int4v*>(&P[18 * 64 + L]); keep(o);
        #pragma unroll
        for (int pl = 0; pl < 4; ++pl) off1[pl] = o[pl];
    }

    // ---- single staging loop over flow tile (36x36=1296, 3 predicated trips).
    // Flow write always; guidance for interior 34x34 reuses in-register v0.
    ushort* w16 = reinterpret_cast<ushort*>(g32 + FBWORDS);
    #pragma unroll
    for (int k = 0; k < 3; ++k) {
        const int i = tid + k * NT;
        if (i < FR * FR) {
            const int ly = i / FR, lx = i - (i / FR) * FR;
            const int y = by0 - 2 + ly, x = bx0 - 2 + lx;
            const bool inimg = (unsigned)y < HH && (unsigned)x < WW;
            float f0 = 0.f, f1 = 0.f;
            if (inimg) {
                f0 = v0b[y * WW + x];
                f1 = v0b[HW + y * WW + x];
            }
            float2v p; p[0] = f0; p[1] = f1;
            f2[ly * FPS2 + lx] = p;

            // guidance for interior items (r = ly-1, cc = lx-1)
            if (ly >= 1 && ly <= GR && lx >= 1 && lx <= GR) {
                const int r = ly - 1, cc = lx - 1;
                uint fbw = 0u;
                ushort wv16 = 0;
                if (inimg) {
                    const float sgx = (-1.0f + x * (2.0f / (WW - 1))) + f0 * (2.0f / WW);
                    const float sgy = (-1.0f + y * (2.0f / (HH - 1))) + f1 * (2.0f / HH);
                    const float ixf = (sgx + 1.0f) * (0.5f * (WW - 1));
                    const float iyf = (sgy + 1.0f) * (0.5f * (HH - 1));
                    const float x0f = floorf(ixf), y0f = floorf(iyf);
                    const int   x0  = (int)x0f,   y0i = (int)y0f;
                    const float wx1 = ixf - x0f, wx0 = 1.0f - wx1;
                    const float wy1 = iyf - y0f, wy0 = 1.0f - wy1;
                    float s0 = 0.f, s1 = 0.f;
                    if (x0 >= 0 && x0 + 1 < WW && y0i >= 0 && y0i + 1 < HH) {
                        const int i00 = y0i * WW + x0;
                        const float2u c0a = *reinterpret_cast<const float2u*>(v2b + i00);
                        const float2u c0b = *reinterpret_cast<const float2u*>(v2b + i00 + WW);
                        const float2u c1a = *reinterpret_cast<const float2u*>(v2b + HW + i00);
                        const float2u c1b = *reinterpret_cast<const float2u*>(v2b + HW + i00 + WW);
                        const float w00 = wy0 * wx0, w01 = wy0 * wx1;
                        const float w10 = wy1 * wx0, w11 = wy1 * wx1;
                        s0 = fmaf(w00, c0a[0], s0);  s1 = fmaf(w00, c1a[0], s1);
                        s0 = fmaf(w01, c0a[1], s0);  s1 = fmaf(w01, c1a[1], s1);
                        s0 = fmaf(w10, c0b[0], s0);  s1 = fmaf(w10, c1b[0], s1);
                        s0 = fmaf(w11, c0b[1], s0);  s1 = fmaf(w11, c1b[1], s1);
                    } else {
                        #pragma unroll
                        for (int cy = 0; cy < 2; ++cy) {
                            const int yc = y0i + cy;
                            const float wy = cy ? wy1 : wy0;
                            if (yc >= 0 && yc < HH) {
                                #pragma unroll
                                for (int cx = 0; cx < 2; ++cx) {
                                    const int xc = x0 + cx;
                                    if (xc >= 0 && xc < WW) {
                                        const float wgt = wy * (cx ? wx1 : wx0);
                                        const int i2 = yc * WW + xc;
                                        s0 = fmaf(wgt, v2b[i2], s0);
                                        s1 = fmaf(wgt, v2b[HW + i2], s1);
                                    }
                                }
                            }
                        }
                    }
                    const float fb0 = f0 + s0;
                    const float fb1 = f1 + s1;
                    const float wv  = __expf(-sqrtf(fmaf(fb0, fb0, fb1 * fb1)));
                    fbw  = (uint)f2bf_rne(fb0) | ((uint)f2bf_rne(fb1) << 16);
                    wv16 = f2bf_rne(wv);
                }
                g32[r * GS2 + cc] = fbw;
                const int rowb = r * (2 * GS2);
                w16[rowb + 2 * cc] = wv16;
                if (cc > 0)   w16[rowb + 2 * cc - 1] = wv16; // high half of word cc-1
                if (cc == 33) w16[rowb + 67] = 0;            // dead element: keep finite
            }
        }
    }
    __syncthreads();

    // ---- 8 groups of 16 px per wave (wave w owns rows 4w..4w+3) ----
    #pragma unroll 2
    for (int g = 0; g < 8; ++g) {
        const int py = 4 * w + (g >> 1);
        const int px = 16 * (g & 1) + c;
        const int gb = py * GS2 + px;

        // B1 frag: 4 u32 word gathers -> short8
        uint4v uw;
        #pragma unroll
        for (int pl = 0; pl < 4; ++pl) uw[pl] = g32[off1[pl] + gb];
        const short8 b1 = *reinterpret_cast<const short8*>(&uw);

        // conv3x3 GEMM (bf16 B, split A), bias in C
        float4v acc1_0 = bi1[0], acc1_1 = bi1[1];
        acc1_0 = MFMA16x32(a1l[0], b1, acc1_0);
        acc1_0 = MFMA16x32(a1h[0], b1, acc1_0);
        acc1_1 = MFMA16x32(a1l[1], b1, acc1_1);
        acc1_1 = MFMA16x32(a1h[1], b1, acc1_1);

        // ReLU + truncation bf16 (hi only; headroom verified) -> conv2 B frag
        short8 b2h;
        #pragma unroll
        for (int r = 0; r < 4; ++r) {
            const float h0 = fmaxf(acc1_0[r], 0.f);
            const float h1 = fmaxf(acc1_1[r], 0.f);
            b2h[r]     = (short)(fu(h0) >> 16);
            b2h[4 + r] = (short)(fu(h1) >> 16);
        }

        // conv1x1 GEMM via K-permuted 16x16x32, hi term only (4 MFMA)
        float4v acc2[4] = {bi2[0], bi2[1], bi2[2], bi2[3]};
        #pragma unroll
        for (int mt = 0; mt < 4; ++mt)
            acc2[mt] = MFMA16x32(a2[mt], b2h, acc2[mt]);

        // combine: 7 x ds_read_b64 (both channels per read), compile-time offsets
        const int pyb   = py * FPS2 + px;
        const int base0 = pyb + q * FPS2;         // taps (q, 0..4)
        const int b4    = pyb + 4 * FPS2 + q;     // tap  (4, q)

        const float2v p0 = f2[base0];
        const float2v p1 = f2[base0 + 1];
        const float2v p2 = f2[base0 + 2];
        const float2v p3 = f2[base0 + 3];
        const float2v p4 = f2[base0 + 4];
        const float2v pb = f2[b4];
        const float2v pc = f2[base0 + 41];        // (4,4): kern==0 unless q==3

        float s0 = 0.f, s1 = 0.f;
        s0 = fmaf(acc2[0][0], p0[0], s0);  s1 = fmaf(acc2[2][0], p0[1], s1);
        s0 = fmaf(acc2[0][1], p1[0], s0);  s1 = fmaf(acc2[2][1], p1[1], s1);
        s0 = fmaf(acc2[0][2], p2[0], s0);  s1 = fmaf(acc2[2][2], p2[1], s1);
        s0 = fmaf(acc2[0][3], p3[0], s0);  s1 = fmaf(acc2[2][3], p3[1], s1);
        s0 = fmaf(acc2[1][0], p4[0], s0);  s1 = fmaf(acc2[3][0], p4[1], s1);
        s0 = fmaf(acc2[1][1], pb[0], s0);  s1 = fmaf(acc2[3][1], pb[1], s1);
        s0 = fmaf(acc2[1][2], pc[0], s0);  s1 = fmaf(acc2[3][2], pc[1], s1);

        s0 += __shfl_xor(s0, 16);
        s0 += __shfl_xor(s0, 32);
        s1 += __shfl_xor(s1, 16);
        s1 += __shfl_xor(s1, 32);

        if (q == 0) {
            const int y = by0 + py, x = bx0 + px;
            out[((size_t)b * 2 + 0) * HW + y * WW + x] = s0;
            out[((size_t)b * 2 + 1) * HW + y * WW + x] = s1;
        }
    }
}

extern "C" void kernel_launch(void* const* d_in, const int* in_sizes, int n_in,
                              void* d_out, int out_size, void* d_ws, size_t ws_size,
                              hipStream_t stream) {
    const float* v0 = (const float*)d_in[0];
    const float* v2 = (const float*)d_in[1];
    const float* w1 = (const float*)d_in[2];
    const float* b1 = (const float*)d_in[3];
    const float* w2 = (const float*)d_in[4];
    const float* b2 = (const float*)d_in[5];
    uint4v* ws = (uint4v*)d_ws;

    setup_params<<<1, 64, 0, stream>>>(w1, b1, w2, b2, ws);

    dim3 grid(WW / TSX, HH / TSY, BB);
    fused_kernel<<<grid, dim3(NT, 1, 1), 0, stream>>>(v0, v2, ws, (float*)d_out);
}

// Round 22
// 49.555 us; speedup vs baseline: 2.6371x; 1.1597x over previous
//
#include <hip/hip_runtime.h>
#include <math.h>

#define BB  8
#define HH  512
#define WW  512
#define HW  (HH*WW)

#define TSX 32           // tile width
#define TSY 32           // tile height
#define GR  34           // guidance tile (halo 1)
#define GS2 36           // packed guidance row stride (u32 words)
#define FBWORDS (GR*GS2) // fb-plane words (w-plane follows)
#define FR  36           // flow tile (halo 2)
#define FPS2 37          // flow row stride (float2 units)

typedef __attribute__((ext_vector_type(8))) short  short8;
typedef __attribute__((ext_vector_type(4))) float  float4v;
typedef __attribute__((ext_vector_type(2))) float  float2v;
typedef __attribute__((ext_vector_type(2), aligned(4))) float float2u; // 4B-aligned pair
typedef __attribute__((ext_vector_type(4))) int    int4v;
typedef __attribute__((ext_vector_type(4))) uint   uint4v;

#define MFMA16x32(a,b,c) __builtin_amdgcn_mfma_f32_16x16x32_bf16((a),(b),(c),0,0,0)

// launder: force materialization (anti-remat)
template <typename T>
static __device__ __forceinline__ void keep(T& x) { asm volatile("" : "+v"(x)); }

static __device__ __forceinline__ uint  fu(float f) { return __float_as_uint(f); }
static __device__ __forceinline__ float uf(uint u)  { return __uint_as_float(u); }

static __device__ __forceinline__ ushort f2bf_rne(float f) {
    uint u = fu(f);
    u += 0x7fffu + ((u >> 16) & 1u);
    return (ushort)(u >> 16);
}
static __device__ __forceinline__ void split_rne(float f, ushort& hi, ushort& lo) {
    hi = f2bf_rne(f);
    float r = f - uf((uint)hi << 16);
    lo = f2bf_rne(r);
}

// conv2 row-permutation tap (verified r7-r21)
static __device__ __forceinline__ int tap_kk(int mtodd, int qr, int rr) {
    if (!mtodd) return 5 * qr + rr;
    if (rr == 0) return 5 * qr + 4;
    if (rr == 1) return 20 + qr;
    if (rr == 2 && qr == 3) return 24;
    return -1;
}

// conv1 K-slot -> original k (pair-packed scheme, verified r10-r21)
static __device__ __forceinline__ int slot_k(int q, int i) {
    const int p = 4 * q + (i >> 1), e = i & 1;
    if (p <= 8)  return e ? 9 + p : p;
    if (p <= 11) return 18 + 3 * (p - 9) + e;
    if (p <= 14) return e ? -1 : 18 + 3 * (p - 12) + 2;
    return -1;
}

// ===================== setup: per-lane MFMA params -> ws =====================
__global__ __launch_bounds__(64)
void setup_params(const float* __restrict__ w1, const float* __restrict__ b1,
                  const float* __restrict__ w2, const float* __restrict__ b2,
                  uint4v* __restrict__ ws)
{
    const int L = threadIdx.x;
    const int c = L & 15, q = L >> 4;

    #pragma unroll
    for (int t = 0; t < 2; ++t) {
        short8 hi8, lo8;
        #pragma unroll
        for (int i = 0; i < 8; ++i) {
            const int k = slot_k(q, i);
            const float f = (k >= 0) ? w1[(16 * t + c) * 27 + k] : 0.f;
            ushort h_, l_; split_rne(f, h_, l_);
            hi8[i] = (short)h_; lo8[i] = (short)l_;
        }
        *reinterpret_cast<short8*>(&ws[(0 + t) * 64 + L]) = hi8;
        *reinterpret_cast<short8*>(&ws[(2 + t) * 64 + L]) = lo8;
    }
    #pragma unroll
    for (int mt = 0; mt < 4; ++mt) {
        const int ch = mt >> 1;
        const int kk = tap_kk(mt & 1, c >> 2, c & 3);
        short8 a8;
        #pragma unroll
        for (int i = 0; i < 8; ++i) {
            const int oc = (i < 4) ? (4 * q + i) : (16 + 4 * q + (i - 4));
            const float f = (kk >= 0) ? w2[(25 * ch + kk) * 32 + oc] : 0.f;
            a8[i] = (short)f2bf_rne(f);
        }
        *reinterpret_cast<short8*>(&ws[(4 + mt) * 64 + L]) = a8;
    }
    #pragma unroll
    for (int t = 0; t < 2; ++t) {
        float4v v;
        #pragma unroll
        for (int r = 0; r < 4; ++r) v[r] = b1[16 * t + 4 * q + r];
        *reinterpret_cast<float4v*>(&ws[(12 + t) * 64 + L]) = v;
    }
    #pragma unroll
    for (int mt = 0; mt < 4; ++mt) {
        const int ch = mt >> 1;
        float4v v;
        #pragma unroll
        for (int r = 0; r < 4; ++r) {
            const int kk = tap_kk(mt & 1, q, r);
            v[r] = (kk >= 0) ? b2[25 * ch + kk] : 0.f;
        }
        *reinterpret_cast<float4v*>(&ws[(14 + mt) * 64 + L]) = v;
    }
    {
        int4v o;
        #pragma unroll
        for (int pl = 0; pl < 4; ++pl) {
            const int p = 4 * q + pl;
            int off;
            if (p <= 8)       off = (p / 3) * GS2 + (p % 3);        // FB word
            else if (p <= 11) off = FBWORDS + (p - 9) * GS2;        // W (ky,0)
            else if (p <= 14) off = FBWORDS + (p - 12) * GS2 + 2;   // W (ky,2)
            else              off = FBWORDS;                        // pad (dead)
            o[pl] = off;
        }
        *reinterpret_cast<int4v*>(&ws[18 * 64 + L]) = o;
    }
}

// ====== fused: guidance in staging + convs + combine (batch->XCD swizzle) ======
__global__ __launch_bounds__(256, 3)
void fused_kernel(const float* __restrict__ v0,
                  const float* __restrict__ v2,
                  const uint4v* __restrict__ P,
                  float* __restrict__ out)
{
    __shared__ uint    g32[2 * FBWORDS];          // fb-pair plane | w-pair plane
    __shared__ float2v f2[FR * FPS2];             // flow tile, channels interleaved

    // batch->XCD affinity: linear id % 8 selects XCD (round-robin dispatch);
    // arrange id = tile*8 + batch so all blocks of batch b land on XCD b.
    // Each XCD's 4MB L2 then caches exactly its batch's v0+v2 (4MB).
    const int id  = blockIdx.x;
    const int b   = id & 7;
    const int tle = id >> 3;
    const int bx0 = (tle & 15) * TSX;
    const int by0 = (tle >> 4) * TSY;
    const int tid = threadIdx.x;
    const int w   = tid >> 6;
    const int L   = tid & 63;
    const int c   = L & 15;
    const int q   = L >> 4;

    const float* v0b = v0 + (size_t)b * 2 * HW;
    const float* v2b = v2 + (size_t)b * 2 * HW;

    // ---- per-lane params (loaded once) ----
    short8 a1h[2], a1l[2], a2[4];
    #pragma unroll
    for (int t = 0; t < 2; ++t) {
        a1h[t] = *reinterpret_cast<const short8*>(&P[(0 + t) * 64 + L]); keep(a1h[t]);
        a1l[t] = *reinterpret_cast<const short8*>(&P[(2 + t) * 64 + L]); keep(a1l[t]);
    }
    #pragma unroll
    for (int mt = 0; mt < 4; ++mt) {
        a2[mt] = *reinterpret_cast<const short8*>(&P[(4 + mt) * 64 + L]); keep(a2[mt]);
    }
    float4v bi1[2], bi2[4];
    #pragma unroll
    for (int t = 0; t < 2; ++t) {
        bi1[t] = *reinterpret_cast<const float4v*>(&P[(12 + t) * 64 + L]); keep(bi1[t]);
    }
    #pragma unroll
    for (int mt = 0; mt < 4; ++mt) {
        bi2[mt] = *reinterpret_cast<const float4v*>(&P[(14 + mt) * 64 + L]); keep(bi2[mt]);
    }
    int off1[4];
    {
        int4v o = *reinterpret_cast<const int4v*>(&P[18 * 64 + L]); keep(o);
        #pragma unroll
        for (int pl = 0; pl < 4; ++pl) off1[pl] = o[pl];
    }

    // ---- single staging loop over flow tile (36x36=1296, 6 predicated trips).
    // Flow write always; guidance for interior 34x34 reuses in-register v0.
    ushort* w16 = reinterpret_cast<ushort*>(g32 + FBWORDS);
    #pragma unroll
    for (int k = 0; k < 6; ++k) {
        const int i = tid + k * 256;
        if (i < FR * FR) {
            const int ly = i / FR, lx = i - (i / FR) * FR;
            const int y = by0 - 2 + ly, x = bx0 - 2 + lx;
            const bool inimg = (unsigned)y < HH && (unsigned)x < WW;
            float f0 = 0.f, f1 = 0.f;
            if (inimg) {
                f0 = v0b[y * WW + x];
                f1 = v0b[HW + y * WW + x];
            }
            float2v p; p[0] = f0; p[1] = f1;
            f2[ly * FPS2 + lx] = p;

            // guidance for interior items (r = ly-1, cc = lx-1)
            if (ly >= 1 && ly <= GR && lx >= 1 && lx <= GR) {
                const int r = ly - 1, cc = lx - 1;
                uint fbw = 0u;
                ushort wv16 = 0;
                if (inimg) {
                    const float sgx = (-1.0f + x * (2.0f / (WW - 1))) + f0 * (2.0f / WW);
                    const float sgy = (-1.0f + y * (2.0f / (HH - 1))) + f1 * (2.0f / HH);
                    const float ixf = (sgx + 1.0f) * (0.5f * (WW - 1));
                    const float iyf = (sgy + 1.0f) * (0.5f * (HH - 1));
                    const float x0f = floorf(ixf), y0f = floorf(iyf);
                    const int   x0  = (int)x0f,   y0i = (int)y0f;
                    const float wx1 = ixf - x0f, wx0 = 1.0f - wx1;
                    const float wy1 = iyf - y0f, wy0 = 1.0f - wy1;
                    float s0 = 0.f, s1 = 0.f;
                    if (x0 >= 0 && x0 + 1 < WW && y0i >= 0 && y0i + 1 < HH) {
                        const int i00 = y0i * WW + x0;
                        const float2u c0a = *reinterpret_cast<const float2u*>(v2b + i00);
                        const float2u c0b = *reinterpret_cast<const float2u*>(v2b + i00 + WW);
                        const float2u c1a = *reinterpret_cast<const float2u*>(v2b + HW + i00);
                        const float2u c1b = *reinterpret_cast<const float2u*>(v2b + HW + i00 + WW);
                        const float w00 = wy0 * wx0, w01 = wy0 * wx1;
                        const float w10 = wy1 * wx0, w11 = wy1 * wx1;
                        s0 = fmaf(w00, c0a[0], s0);  s1 = fmaf(w00, c1a[0], s1);
                        s0 = fmaf(w01, c0a[1], s0);  s1 = fmaf(w01, c1a[1], s1);
                        s0 = fmaf(w10, c0b[0], s0);  s1 = fmaf(w10, c1b[0], s1);
                        s0 = fmaf(w11, c0b[1], s0);  s1 = fmaf(w11, c1b[1], s1);
                    } else {
                        #pragma unroll
                        for (int cy = 0; cy < 2; ++cy) {
                            const int yc = y0i + cy;
                            const float wy = cy ? wy1 : wy0;
                            if (yc >= 0 && yc < HH) {
                                #pragma unroll
                                for (int cx = 0; cx < 2; ++cx) {
                                    const int xc = x0 + cx;
                                    if (xc >= 0 && xc < WW) {
                                        const float wgt = wy * (cx ? wx1 : wx0);
                                        const int i2 = yc * WW + xc;
                                        s0 = fmaf(wgt, v2b[i2], s0);
                                        s1 = fmaf(wgt, v2b[HW + i2], s1);
                                    }
                                }
                            }
                        }
                    }
                    const float fb0 = f0 + s0;
                    const float fb1 = f1 + s1;
                    const float wv  = __expf(-sqrtf(fmaf(fb0, fb0, fb1 * fb1)));
                    fbw  = (uint)f2bf_rne(fb0) | ((uint)f2bf_rne(fb1) << 16);
                    wv16 = f2bf_rne(wv);
                }
                g32[r * GS2 + cc] = fbw;
                const int rowb = r * (2 * GS2);
                w16[rowb + 2 * cc] = wv16;
                if (cc > 0)   w16[rowb + 2 * cc - 1] = wv16; // high half of word cc-1
                if (cc == 33) w16[rowb + 67] = 0;            // dead element: keep finite
            }
        }
    }
    __syncthreads();

    // ---- 16 groups of 16 px per wave ----
    #pragma unroll 2
    for (int g = 0; g < 16; ++g) {
        const int py = 8 * w + (g >> 1);
        const int px = 16 * (g & 1) + c;
        const int gb = py * GS2 + px;

        // B1 frag: 4 u32 word gathers -> short8
        uint4v uw;
        #pragma unroll
        for (int pl = 0; pl < 4; ++pl) uw[pl] = g32[off1[pl] + gb];
        const short8 b1 = *reinterpret_cast<const short8*>(&uw);

        // conv3x3 GEMM (bf16 B, split A), bias in C
        float4v acc1_0 = bi1[0], acc1_1 = bi1[1];
        acc1_0 = MFMA16x32(a1l[0], b1, acc1_0);
        acc1_0 = MFMA16x32(a1h[0], b1, acc1_0);
        acc1_1 = MFMA16x32(a1l[1], b1, acc1_1);
        acc1_1 = MFMA16x32(a1h[1], b1, acc1_1);

        // ReLU + truncation bf16 (hi only; headroom verified) -> conv2 B frag
        short8 b2h;
        #pragma unroll
        for (int r = 0; r < 4; ++r) {
            const float h0 = fmaxf(acc1_0[r], 0.f);
            const float h1 = fmaxf(acc1_1[r], 0.f);
            b2h[r]     = (short)(fu(h0) >> 16);
            b2h[4 + r] = (short)(fu(h1) >> 16);
        }

        // conv1x1 GEMM via K-permuted 16x16x32, hi term only (4 MFMA)
        float4v acc2[4] = {bi2[0], bi2[1], bi2[2], bi2[3]};
        #pragma unroll
        for (int mt = 0; mt < 4; ++mt)
            acc2[mt] = MFMA16x32(a2[mt], b2h, acc2[mt]);

        // combine: 7 x ds_read_b64 (both channels per read), compile-time offsets
        const int pyb   = py * FPS2 + px;
        const int base0 = pyb + q * FPS2;         // taps (q, 0..4)
        const int b4    = pyb + 4 * FPS2 + q;     // tap  (4, q)

        const float2v p0 = f2[base0];
        const float2v p1 = f2[base0 + 1];
        const float2v p2 = f2[base0 + 2];
        const float2v p3 = f2[base0 + 3];
        const float2v p4 = f2[base0 + 4];
        const float2v pb = f2[b4];
        const float2v pc = f2[base0 + 41];        // (4,4): kern==0 unless q==3

        float s0 = 0.f, s1 = 0.f;
        s0 = fmaf(acc2[0][0], p0[0], s0);  s1 = fmaf(acc2[2][0], p0[1], s1);
        s0 = fmaf(acc2[0][1], p1[0], s0);  s1 = fmaf(acc2[2][1], p1[1], s1);
        s0 = fmaf(acc2[0][2], p2[0], s0);  s1 = fmaf(acc2[2][2], p2[1], s1);
        s0 = fmaf(acc2[0][3], p3[0], s0);  s1 = fmaf(acc2[2][3], p3[1], s1);
        s0 = fmaf(acc2[1][0], p4[0], s0);  s1 = fmaf(acc2[3][0], p4[1], s1);
        s0 = fmaf(acc2[1][1], pb[0], s0);  s1 = fmaf(acc2[3][1], pb[1], s1);
        s0 = fmaf(acc2[1][2], pc[0], s0);  s1 = fmaf(acc2[3][2], pc[1], s1);

        s0 += __shfl_xor(s0, 16);
        s0 += __shfl_xor(s0, 32);
        s1 += __shfl_xor(s1, 16);
        s1 += __shfl_xor(s1, 32);

        if (q == 0) {
            const int y = by0 + py, x = bx0 + px;
            out[((size_t)b * 2 + 0) * HW + y * WW + x] = s0;
            out[((size_t)b * 2 + 1) * HW + y * WW + x] = s1;
        }
    }
}

extern "C" void kernel_launch(void* const* d_in, const int* in_sizes, int n_in,
                              void* d_out, int out_size, void* d_ws, size_t ws_size,
                              hipStream_t stream) {
    const float* v0 = (const float*)d_in[0];
    const float* v2 = (const float*)d_in[1];
    const float* w1 = (const float*)d_in[2];
    const float* b1 = (const float*)d_in[3];
    const float* w2 = (const float*)d_in[4];
    const float* b2 = (const float*)d_in[5];
    uint4v* ws = (uint4v*)d_ws;

    setup_params<<<1, 64, 0, stream>>>(w1, b1, w2, b2, ws);

    // 1D grid: id = tile*8 + batch  ->  id%8 = batch = XCD (round-robin)
    fused_kernel<<<dim3((WW / TSX) * (HH / TSY) * BB, 1, 1), dim3(256, 1, 1), 0, stream>>>(
        v0, v2, ws, (float*)d_out);
}